// Round 10
// baseline (364.306 us; speedup 1.0000x reference)
//
#include <hip/hip_runtime.h>
#include <stdint.h>

#define DIMC 1024
#define HEADS 16
#define HD 64
#define HIDDENC 4096
#define BATCH 2
#define SEQ 2048
#define MTOK (BATCH*SEQ)

typedef __bf16 bf16x8 __attribute__((ext_vector_type(8)));
typedef float f32x4 __attribute__((ext_vector_type(4)));

__device__ __forceinline__ float bf2f(unsigned short u) {
    union { unsigned int u; float f; } v; v.u = ((unsigned int)u) << 16; return v.f;
}
__device__ __forceinline__ unsigned short f2bf(float f) {
    union { float f; unsigned int u; } v; v.f = f;
    unsigned int r = v.u + 0x7fffu + ((v.u >> 16) & 1u);
    return (unsigned short)(r >> 16);
}
// pack 2 f32 -> 2 bf16 (RNE), src0 -> low half (T12 recipe, guide-verified)
__device__ __forceinline__ unsigned int cvt_pk_bf16(float lo, float hi) {
    unsigned int r;
    asm("v_cvt_pk_bf16_f32 %0, %1, %2" : "=v"(r) : "v"(lo), "v"(hi));
    return r;
}
// 2^x (log2e is pre-folded into the Q scale)
__device__ __forceinline__ float exp2_fast(float x) {
#if __has_builtin(__builtin_amdgcn_exp2f)
    return __builtin_amdgcn_exp2f(x);
#else
    float r;
    asm("v_exp_f32 %0, %1" : "=v"(r) : "v"(x));
    return r;
#endif
}

#define GLOAD_LDS(g, l) \
    __builtin_amdgcn_global_load_lds( \
        (const __attribute__((address_space(1))) void*)(g), \
        (__attribute__((address_space(3))) void*)(l), 16, 0, 0)

// ---------------------------------------------------------------------------
// Weight transpose tile: fp32 (K x N) -> bf16 (N x K).
// ---------------------------------------------------------------------------
__device__ __forceinline__ void tp_tile(const float* __restrict__ in,
                                        unsigned short* __restrict__ out,
                                        int K, int N, int tn, int tk, int tid,
                                        unsigned short (*tile)[65]) {
    for (int c = tid; c < 1024; c += 256) {
        int r = c >> 4, coff = (c & 15) * 4;
        float4 v = *(const float4*)(in + (size_t)(tk + r) * N + tn + coff);
        tile[r][coff + 0] = f2bf(v.x);
        tile[r][coff + 1] = f2bf(v.y);
        tile[r][coff + 2] = f2bf(v.z);
        tile[r][coff + 3] = f2bf(v.w);
    }
    __syncthreads();
    for (int c = tid; c < 512; c += 256) {
        int rn = c >> 3, off = (c & 7) * 8;
        unsigned short tmp[8];
        #pragma unroll
        for (int j = 0; j < 8; j++) tmp[j] = tile[off + j][rn];
        *(uint4*)(out + (size_t)(tn + rn) * K + tk + off) = *(uint4*)tmp;
    }
}

// ---------------------------------------------------------------------------
// LayerNorm row body (shared by fused_pre and ln_kernel).
// ---------------------------------------------------------------------------
__device__ __forceinline__ void ln_row(const float* __restrict__ inp,
                                       const float* __restrict__ w,
                                       const float* __restrict__ b,
                                       unsigned short* __restrict__ out,
                                       int row, int tid, float* red) {
    int base = tid * 4;
    float4 v = *(const float4*)(inp + (size_t)row * DIMC + base);
    float x[4] = {v.x, v.y, v.z, v.w};
    float s1 = x[0] + x[1] + x[2] + x[3];
    float s2 = x[0]*x[0] + x[1]*x[1] + x[2]*x[2] + x[3]*x[3];
    #pragma unroll
    for (int off = 32; off > 0; off >>= 1) {
        s1 += __shfl_xor(s1, off);
        s2 += __shfl_xor(s2, off);
    }
    int wv = tid >> 6;
    if ((tid & 63) == 0) { red[wv] = s1; red[4 + wv] = s2; }
    __syncthreads();
    s1 = red[0] + red[1] + red[2] + red[3];
    s2 = red[4] + red[5] + red[6] + red[7];
    float mean = s1 * (1.0f / DIMC);
    float var  = s2 * (1.0f / DIMC) - mean * mean;
    float rstd = rsqrtf(var + 1e-5f);
    float4 wv4 = *(const float4*)(w + base);
    float4 bv4 = *(const float4*)(b + base);
    ushort4 o;
    o.x = f2bf((x[0] - mean) * rstd * wv4.x + bv4.x);
    o.y = f2bf((x[1] - mean) * rstd * wv4.y + bv4.y);
    o.z = f2bf((x[2] - mean) * rstd * wv4.z + bv4.z);
    o.w = f2bf((x[3] - mean) * rstd * wv4.w + bv4.w);
    *(ushort4*)(out + (size_t)row * DIMC + base) = o;
}

// ---------------------------------------------------------------------------
// fused_pre (R10): all 4 weight transposes + LN1 in ONE dispatch (they are
// independent: transposes read weights, LN1 reads x) -> saves a full drain.
// Blocks [0,3072): transposes; [3072,7168): LN1 rows.
// ---------------------------------------------------------------------------
__global__ __launch_bounds__(256) void fused_pre(
    const float* __restrict__ qkvw, const float* __restrict__ projw,
    const float* __restrict__ fc1w, const float* __restrict__ fc2w,
    unsigned short* __restrict__ qkv_wT, unsigned short* __restrict__ proj_wT,
    unsigned short* __restrict__ fc1_wT, unsigned short* __restrict__ fc2_wT,
    const float* __restrict__ x, const float* __restrict__ ln1w,
    const float* __restrict__ ln1b, unsigned short* __restrict__ ln_out) {
    __shared__ unsigned short tile[64][65];
    __shared__ float red[8];
    int id = blockIdx.x, tid = threadIdx.x;
    if (id < 768) {
        tp_tile(qkvw, qkv_wT, 1024, 3072, (id % 48) * 64, (id / 48) * 64, tid, tile);
    } else if (id < 1024) {
        id -= 768;
        tp_tile(projw, proj_wT, 1024, 1024, (id % 16) * 64, (id / 16) * 64, tid, tile);
    } else if (id < 2048) {
        id -= 1024;
        tp_tile(fc1w, fc1_wT, 1024, 4096, (id % 64) * 64, (id / 64) * 64, tid, tile);
    } else if (id < 3072) {
        id -= 2048;
        tp_tile(fc2w, fc2_wT, 4096, 1024, (id % 16) * 64, (id / 16) * 64, tid, tile);
    } else {
        ln_row(x, ln1w, ln1b, ln_out, id - 3072, tid, red);
    }
}

// ---------------------------------------------------------------------------
// LayerNorm kernel (LN2).
// ---------------------------------------------------------------------------
__global__ __launch_bounds__(256) void ln_kernel(const float* __restrict__ inp,
                                                 const float* __restrict__ w,
                                                 const float* __restrict__ b,
                                                 unsigned short* __restrict__ out) {
    __shared__ float red[8];
    ln_row(inp, w, b, out, blockIdx.x, threadIdx.x, red);
}

// ---------------------------------------------------------------------------
// bf16 MFMA GEMM: C(M x N) = A(M x K) @ BT(N x K)^T.
// Tile TM x TN, 4 waves (2x2), XOR-swizzled LDS, global_load_lds staging,
// double-buffered with counted vmcnt (R4).
//
// Mapping (A/B-measured):
//  - QKV (128x128), FC1 (128x64, R9): 2D dim3 grid. R5 rectangle REGRESSED
//    FC1 (lockstep A-panel reads); dim3 spreads co-resident blocks.
//  - PROJ/FC2 (64x64): 1D XCD rectangle (MG=4 x NG=2). R4: naive dim3 gave
//    A-dup=8, FETCH 143MB.
// ---------------------------------------------------------------------------
enum { EP_QKV = 0, EP_PROJ = 1, EP_FC1 = 2, EP_FC2 = 3 };

template <int MODE, int N, int K, int TM, int TN, int BK>
__global__ __launch_bounds__(256) void gemm_kernel(
    const unsigned short* __restrict__ A,
    const unsigned short* __restrict__ BT,
    const float* __restrict__ bias,
    const float* __restrict__ res,      // fp32 residual (PROJ: x, FC2: x1)
    void* __restrict__ out0,
    unsigned short* __restrict__ q_buf,
    unsigned short* __restrict__ k_buf,
    unsigned short* __restrict__ v_buf) {  // QKV: vT_buf [bh][d][t]
    constexpr int MI = TM / 32;
    constexpr int NJ = TN / 32;
    constexpr int CPR = BK / 8;
    constexpr int NT = K / BK;
    constexpr int N_LD = (TM + TN) * BK / 2048;
    static_assert(N_LD == 8 || N_LD == 6 || N_LD == 4, "vmcnt literal");
    constexpr int NX = N / TN;
    constexpr int NY = MTOK / TM;
    constexpr int MG = 4, NG = 2;
    constexpr int NXG = NX / NG, NYG = NY / MG;

    __shared__ __align__(16) unsigned short As[2 * TM * BK];
    __shared__ __align__(16) unsigned short Bs[2 * TN * BK];
    const int tid = threadIdx.x;

    int m0, n0;
    if constexpr (MODE == EP_PROJ || MODE == EP_FC2) {
        const int jb = blockIdx.x;
        const int xcd = jb & 7;
        const int tb = jb >> 3;
        const int mg = xcd >> 1, ng = xcd & 1;
        m0 = (mg * NYG + tb / NXG) * TM;
        n0 = (ng * NXG + tb % NXG) * TN;
    } else {
        m0 = blockIdx.y * TM;
        n0 = blockIdx.x * TN;
    }

    const int wave = tid >> 6, lane = tid & 63;
    const int wm = wave >> 1, wn = wave & 1;
    const int quad = lane >> 4, l16 = lane & 15;
    const int swz = l16 & (CPR - 1);

    f32x4 acc[MI][NJ] = {};

    auto stage = [&](int t, int b) {
        const size_t kk = (size_t)t * BK;
        #pragma unroll
        for (int it = 0; it < TM * BK / 2048; ++it) {
            int c = tid + 256 * it;
            int row = c / CPR, jj = c % CPR;
            int col8 = (jj ^ (row & (CPR - 1))) * 8;
            GLOAD_LDS(A + (size_t)(m0 + row) * K + kk + col8,
                      As + (size_t)b * TM * BK + (size_t)c * 8);
        }
        #pragma unroll
        for (int it = 0; it < TN * BK / 2048; ++it) {
            int c = tid + 256 * it;
            int row = c / CPR, jj = c % CPR;
            int col8 = (jj ^ (row & (CPR - 1))) * 8;
            GLOAD_LDS(BT + (size_t)(n0 + row) * K + kk + col8,
                      Bs + (size_t)b * TN * BK + (size_t)c * 8);
        }
    };

    stage(0, 0);
    for (int t = 0; t < NT; ++t) {
        const int cur = t & 1;
        if (t + 1 < NT) {
            stage(t + 1, cur ^ 1);
            if constexpr (N_LD == 8)      asm volatile("s_waitcnt vmcnt(8)" ::: "memory");
            else if constexpr (N_LD == 6) asm volatile("s_waitcnt vmcnt(6)" ::: "memory");
            else                          asm volatile("s_waitcnt vmcnt(4)" ::: "memory");
        } else {
            asm volatile("s_waitcnt vmcnt(0)" ::: "memory");
        }
        __builtin_amdgcn_s_barrier();

        const unsigned short* Asb = As + (size_t)cur * TM * BK;
        const unsigned short* Bsb = Bs + (size_t)cur * TN * BK;
        #pragma unroll
        for (int kk2 = 0; kk2 < BK / 32; ++kk2) {
            bf16x8 af[MI], bfv[NJ];
            #pragma unroll
            for (int i = 0; i < MI; i++) {
                int row = 16 * MI * wm + 16 * i + l16;
                int sj = (4 * kk2 + quad) ^ swz;
                af[i] = *(const bf16x8*)&Asb[row * BK + sj * 8];
            }
            #pragma unroll
            for (int j = 0; j < NJ; j++) {
                int row = 16 * NJ * wn + 16 * j + l16;
                int sj = (4 * kk2 + quad) ^ swz;
                bfv[j] = *(const bf16x8*)&Bsb[row * BK + sj * 8];
            }
            #pragma unroll
            for (int i = 0; i < MI; i++)
                #pragma unroll
                for (int j = 0; j < NJ; j++)
                    acc[i][j] = __builtin_amdgcn_mfma_f32_16x16x32_bf16(af[i], bfv[j], acc[i][j], 0, 0, 0);
        }
        asm volatile("s_waitcnt lgkmcnt(0)" ::: "memory");
        __builtin_amdgcn_s_barrier();
    }

    #pragma unroll
    for (int i = 0; i < MI; i++) {
        #pragma unroll
        for (int j = 0; j < NJ; j++) {
            int nl = n0 + 16 * NJ * wn + 16 * j + l16;
            if (MODE == EP_QKV) {
                int which = nl >> 10, rem = nl & 1023;
                int hh = rem >> 6, d = rem & 63;
                int ml0 = m0 + 16 * MI * wm + 16 * i + quad * 4;
                int bb2 = ml0 >> 11, t0 = ml0 & 2047;
                int bh = bb2 * HEADS + hh;
                if (which == 2) {
                    uint2 w;
                    w.x = cvt_pk_bf16(acc[i][j][0], acc[i][j][1]);
                    w.y = cvt_pk_bf16(acc[i][j][2], acc[i][j][3]);
                    *(uint2*)(v_buf + ((size_t)bh * HD + d) * SEQ + t0) = w;
                } else if (which == 0) {
                    #pragma unroll
                    for (int r = 0; r < 4; r++)
                        q_buf[((size_t)bh * SEQ + t0 + r) * HD + d] =
                            f2bf(acc[i][j][r] * 0.18033688011112042f);
                } else {
                    #pragma unroll
                    for (int r = 0; r < 4; r++)
                        k_buf[((size_t)bh * SEQ + t0 + r) * HD + d] = f2bf(acc[i][j][r]);
                }
            } else {
                float bval = bias[nl];
                #pragma unroll
                for (int r = 0; r < 4; r++) {
                    int ml = m0 + 16 * MI * wm + 16 * i + quad * 4 + r;
                    float v = acc[i][j][r];
                    if (MODE == EP_PROJ) {
                        float* x1 = (float*)out0;
                        x1[(size_t)ml * DIMC + nl] = res[(size_t)ml * DIMC + nl] + v + bval;
                    } else if (MODE == EP_FC1) {
                        float g = v + bval;
                        float u = 1.5957691216f * (g + 0.044715f * g * g * g);
                        float gv = g / (1.0f + __expf(-u));
                        ((unsigned short*)out0)[(size_t)ml * HIDDENC + nl] = f2bf(gv);
                    } else {
                        ((float*)out0)[(size_t)ml * DIMC + nl] =
                            res[(size_t)ml * DIMC + nl] + v + bval;
                    }
                }
            }
        }
    }
}

// ---------------------------------------------------------------------------
// Flash attention, pair-balanced + 2-WAY SPLIT-K (R10).
// R9 post-mortem: combine-free attention caps at 2048 waves (2/SIMD); occ 16%
// with ~50% stall. 2-way split by kt PARITY doubles waves to 4096 (4/SIMD):
// block (pair p, bh, chunk c): kt = c, c+2, ... -> 16/17 units per block,
// uniform. Writes UNNORMALIZED bf16 O (R6-proven) + lsum; combine divides by
// l0+l1. launch_bounds(256,4): LDS 35KB -> 4 blocks/CU; VGPR cap 128.
//
// Key-padding: masked keys get CONSTANT 1e-13 (uniform when row fully masked,
// matching ref fp32 +(-1e9)). Swapped QK^T; P via cvt_pk+ds_write_b64 into
// wave-private XOR-swizzled Ps; PV A-read = contiguous ds_read_b128.
// ---------------------------------------------------------------------------
#define KP 72
#define PMASK 1e-13f
__global__ __launch_bounds__(256, 4) void attn_partial2(
    const unsigned short* __restrict__ q_buf,
    const unsigned short* __restrict__ k_buf,
    const unsigned short* __restrict__ vT_buf,
    const int* __restrict__ mask,
    unsigned short* __restrict__ opart,   // [c][bh][t][d], bf16, 16MB
    float* __restrict__ l_part) {         // [c][bh][t], f32
    __shared__ __align__(16) unsigned short Ks[64 * KP];
    __shared__ __align__(16) unsigned short Vs[64 * KP];
    __shared__ __align__(16) unsigned short PsA[4 * 16 * 64];
    __shared__ __align__(16) unsigned short PsB[4 * 16 * 64];
    __shared__ __align__(16) float Msf[64];

    // decode: xcd = j&7 pins bh group to XCD; c = chunk parity; p = pair.
    const int j = blockIdx.x;            // 0..1023
    const int xcd = j & 7;
    const int t = j >> 3;                // 0..127
    const int c = t & 1;
    const int t2 = t >> 1;               // 0..63
    const int bhg = t2 & 3;
    const int p = t2 >> 2;               // 0..15
    const int bh = bhg * 8 + xcd;        // 0..31
    const int bb = bh >> 4, h = bh & 15;
    const int qa = 31 - p, qb = p;       // qa > qb always
    const int kta = qa + 1;

    const int tid = threadIdx.x, wave = tid >> 6, lane = tid & 63;
    const int quad = lane >> 4, l16 = lane & 15;
    const unsigned short* qp = q_buf + (size_t)bh * SEQ * HD;
    const unsigned short* kp = k_buf + (size_t)bh * SEQ * HD;
    const unsigned short* vp = vT_buf + (size_t)bh * HD * SEQ;
    const int* mrow_ptr = mask + bb * SEQ;

    const int qrow_a = qa * 64 + wave * 16 + l16;
    const int qrow_b = qb * 64 + wave * 16 + l16;
    bf16x8 qfa[2], qfb[2];
    qfa[0] = *(const bf16x8*)(qp + (size_t)qrow_a * HD + 8 * quad);
    qfa[1] = *(const bf16x8*)(qp + (size_t)qrow_a * HD + 32 + 8 * quad);
    qfb[0] = *(const bf16x8*)(qp + (size_t)qrow_b * HD + 8 * quad);
    qfb[1] = *(const bf16x8*)(qp + (size_t)qrow_b * HD + 32 + 8 * quad);

    f32x4 oa[4] = {}, ob4[4] = {};
    float lsa = 0.0f, lsb = 0.0f;

    const int r0 = tid >> 3, c0 = (tid & 7) * 8;
    const int r1 = r0 + 32;

    char* psA = (char*)PsA + wave * 2048 + l16 * 128;
    char* psB = (char*)PsB + wave * 2048 + l16 * 128;
    const int swz = (l16 & 7) << 4;

    // solo pass (tile a only; kt > qb)
    auto solo_pass = [&](int kt) {
        f32x4 sc[4];
        __builtin_amdgcn_s_setprio(1);
        #pragma unroll
        for (int ct = 0; ct < 4; ct++) {
            f32x4 z = {};
            #pragma unroll
            for (int ss = 0; ss < 2; ss++) {
                bf16x8 kf = *(const bf16x8*)&Ks[(16 * ct + l16) * KP + 32 * ss + 8 * quad];
                z = __builtin_amdgcn_mfma_f32_16x16x32_bf16(kf, qfa[ss], z, 0, 0, 0);
            }
            sc[ct] = z;
        }
        __builtin_amdgcn_s_setprio(0);

        const bool diag = (kt == qa);
        #pragma unroll
        for (int ct = 0; ct < 4; ct++) {
            float4 mq = *(const float4*)&Msf[16 * ct + 4 * quad];
            float mfs[4] = {mq.x, mq.y, mq.z, mq.w};
            const int kg0 = kt * 64 + 16 * ct + 4 * quad;
            float pv4[4];
            #pragma unroll
            for (int r = 0; r < 4; r++) {
                float pw = (mfs[r] != 0.0f) ? PMASK : exp2_fast(sc[ct][r]);
                if (diag && (kg0 + r) > qrow_a) pw = 0.0f;
                lsa += pw;
                pv4[r] = pw;
            }
            uint2 w;
            w.x = cvt_pk_bf16(pv4[0], pv4[1]);
            w.y = cvt_pk_bf16(pv4[2], pv4[3]);
            *(uint2*)(psA + ((quad * 8 + ct * 32) ^ swz)) = w;
        }
        asm volatile("" ::: "memory");

        __builtin_amdgcn_s_setprio(1);
        #pragma unroll
        for (int ss = 0; ss < 2; ss++) {
            bf16x8 pf = *(const bf16x8*)(psA + ((ss * 64 + quad * 16) ^ swz));
            #pragma unroll
            for (int dt = 0; dt < 4; dt++) {
                bf16x8 vf = *(const bf16x8*)&Vs[(16 * dt + l16) * KP + 32 * ss + 8 * quad];
                oa[dt] = __builtin_amdgcn_mfma_f32_16x16x32_bf16(pf, vf, oa[dt], 0, 0, 0);
            }
        }
        __builtin_amdgcn_s_setprio(0);
        asm volatile("" ::: "memory");
    };

    // pair pass (kt <= qb): shared kf/vf loads, dual Ps.
    auto pair_pass = [&](int kt) {
        f32x4 sa[4], sb[4];
        __builtin_amdgcn_s_setprio(1);
        #pragma unroll
        for (int ct = 0; ct < 4; ct++) {
            f32x4 za = {}, zb = {};
            #pragma unroll
            for (int ss = 0; ss < 2; ss++) {
                bf16x8 kf = *(const bf16x8*)&Ks[(16 * ct + l16) * KP + 32 * ss + 8 * quad];
                za = __builtin_amdgcn_mfma_f32_16x16x32_bf16(kf, qfa[ss], za, 0, 0, 0);
                zb = __builtin_amdgcn_mfma_f32_16x16x32_bf16(kf, qfb[ss], zb, 0, 0, 0);
            }
            sa[ct] = za; sb[ct] = zb;
        }
        __builtin_amdgcn_s_setprio(0);

        const bool diag_b = (kt == qb);
        #pragma unroll
        for (int ct = 0; ct < 4; ct++) {
            float4 mq = *(const float4*)&Msf[16 * ct + 4 * quad];
            float mfs[4] = {mq.x, mq.y, mq.z, mq.w};
            const int kg0 = kt * 64 + 16 * ct + 4 * quad;
            float pa4[4], pb4[4];
            #pragma unroll
            for (int r = 0; r < 4; r++) {
                float pa = (mfs[r] != 0.0f) ? PMASK : exp2_fast(sa[ct][r]);
                float pb = (mfs[r] != 0.0f) ? PMASK : exp2_fast(sb[ct][r]);
                if (diag_b && (kg0 + r) > qrow_b) pb = 0.0f;
                lsa += pa; lsb += pb;
                pa4[r] = pa; pb4[r] = pb;
            }
            uint2 wa, wb;
            wa.x = cvt_pk_bf16(pa4[0], pa4[1]);
            wa.y = cvt_pk_bf16(pa4[2], pa4[3]);
            wb.x = cvt_pk_bf16(pb4[0], pb4[1]);
            wb.y = cvt_pk_bf16(pb4[2], pb4[3]);
            *(uint2*)(psA + ((quad * 8 + ct * 32) ^ swz)) = wa;
            *(uint2*)(psB + ((quad * 8 + ct * 32) ^ swz)) = wb;
        }
        asm volatile("" ::: "memory");

        __builtin_amdgcn_s_setprio(1);
        #pragma unroll
        for (int ss = 0; ss < 2; ss++) {
            bf16x8 pfa = *(const bf16x8*)(psA + ((ss * 64 + quad * 16) ^ swz));
            bf16x8 pfb = *(const bf16x8*)(psB + ((ss * 64 + quad * 16) ^ swz));
            #pragma unroll
            for (int dt = 0; dt < 4; dt++) {
                bf16x8 vf = *(const bf16x8*)&Vs[(16 * dt + l16) * KP + 32 * ss + 8 * quad];
                oa[dt]  = __builtin_amdgcn_mfma_f32_16x16x32_bf16(pfa, vf, oa[dt], 0, 0, 0);
                ob4[dt] = __builtin_amdgcn_mfma_f32_16x16x32_bf16(pfb, vf, ob4[dt], 0, 0, 0);
            }
        }
        __builtin_amdgcn_s_setprio(0);
        asm volatile("" ::: "memory");
    };

    // prefetch first tile (kt = c); Msf holds 1.0 = masked, 0.0 = visible
    uint4 pk0, pk1, pv0, pv1; float pmv = 0.0f;
    pk0 = *(const uint4*)(kp + (size_t)(c * 64 + r0) * HD + c0);
    pk1 = *(const uint4*)(kp + (size_t)(c * 64 + r1) * HD + c0);
    pv0 = *(const uint4*)(vp + (size_t)r0 * SEQ + c * 64 + c0);
    pv1 = *(const uint4*)(vp + (size_t)r1 * SEQ + c * 64 + c0);
    if (tid < 64) pmv = mrow_ptr[c * 64 + tid] ? 1.0f : 0.0f;

    for (int kt = c; kt < kta; kt += 2) {
        __syncthreads();
        *(uint4*)&Ks[r0 * KP + c0] = pk0;
        *(uint4*)&Ks[r1 * KP + c0] = pk1;
        *(uint4*)&Vs[r0 * KP + c0] = pv0;
        *(uint4*)&Vs[r1 * KP + c0] = pv1;
        if (tid < 64) Msf[tid] = pmv;
        if (kt + 2 < kta) {
            pk0 = *(const uint4*)(kp + (size_t)((kt + 2) * 64 + r0) * HD + c0);
            pk1 = *(const uint4*)(kp + (size_t)((kt + 2) * 64 + r1) * HD + c0);
            pv0 = *(const uint4*)(vp + (size_t)r0 * SEQ + (kt + 2) * 64 + c0);
            pv1 = *(const uint4*)(vp + (size_t)r1 * SEQ + (kt + 2) * 64 + c0);
            if (tid < 64) pmv = mrow_ptr[(kt + 2) * 64 + tid] ? 1.0f : 0.0f;
        }
        __syncthreads();

        if (kt <= qb) pair_pass(kt);
        else          solo_pass(kt);
    }

    // store UNNORMALIZED O (staged via wave-private PsA for full-line writes)
    // + per-chunk lsum. Combine kernel normalizes by l0+l1.
    unsigned short* Ls = PsA + wave * 1024;
    auto finishp = [&](const f32x4* o, float ls, int qt_) {
        ls += __shfl_xor(ls, 16);
        ls += __shfl_xor(ls, 32);
        if (lane < 16)
            l_part[(size_t)(c * 32 + bh) * SEQ + qt_ * 64 + wave * 16 + lane] = ls;
        #pragma unroll
        for (int dt = 0; dt < 4; dt++)
            #pragma unroll
            for (int r = 0; r < 4; r++)
                Ls[(quad * 4 + r) * 64 + 16 * dt + l16] = f2bf(o[dt][r]);
        asm volatile("" ::: "memory");
        unsigned short* obp = opart +
            ((size_t)(c * 32 + bh) * SEQ + qt_ * 64 + wave * 16) * 64;
        *(uint4*)(obp + lane * 8) = *(const uint4*)&Ls[lane * 8];
        *(uint4*)(obp + 512 + lane * 8) = *(const uint4*)&Ls[512 + lane * 8];
        asm volatile("" ::: "memory");
    };
    finishp(oa, lsa, qa);
    finishp(ob4, lsb, qb);
}

// ---------------------------------------------------------------------------
// Combine the 2 split-K chunks: attn_o = (O0 + O1) / (l0 + l1), bf16.
// One block per (qt, h, b); vectorized uint4 (R6-proven pattern, n=2).
// ---------------------------------------------------------------------------
__global__ __launch_bounds__(256) void attn_combine2(
    const unsigned short* __restrict__ opart,
    const float* __restrict__ l_part,
    unsigned short* __restrict__ attn_o) {
    const int qt = blockIdx.x, h = blockIdx.y, bb = blockIdx.z;
    const int bh = bb * HEADS + h;
    const int tid = threadIdx.x;
    __shared__ float linv[64];
    if (tid < 64) {
        float l0 = l_part[(size_t)bh * SEQ + qt * 64 + tid];
        float l1 = l_part[(size_t)(32 + bh) * SEQ + qt * 64 + tid];
        linv[tid] = 1.0f / (l0 + l1);
    }
    __syncthreads();
    const unsigned short* o0 = opart + ((size_t)bh * SEQ + qt * 64) * 64;
    const unsigned short* o1 = opart + ((size_t)(32 + bh) * SEQ + qt * 64) * 64;
    #pragma unroll
    for (int it = 0; it < 2; it++) {
        int idx = (it * 256 + tid) * 8;      // 0..4088
        int row = idx >> 6, d = idx & 63;
        uint4 va = *(const uint4*)(o0 + idx);
        uint4 vb = *(const uint4*)(o1 + idx);
        const unsigned short* pa = (const unsigned short*)&va;
        const unsigned short* pb = (const unsigned short*)&vb;
        float sc = linv[row];
        unsigned short tmp[8];
        #pragma unroll
        for (int e = 0; e < 8; e++)
            tmp[e] = f2bf((bf2f(pa[e]) + bf2f(pb[e])) * sc);
        *(uint4*)(attn_o + ((size_t)(bb * SEQ + qt * 64 + row)) * DIMC + h * HD + d) =
            *(uint4*)tmp;
    }
}

// ---------------------------------------------------------------------------
extern "C" void kernel_launch(void* const* d_in, const int* in_sizes, int n_in,
                              void* d_out, int out_size, void* d_ws, size_t ws_size,
                              hipStream_t stream) {
    const float* x     = (const float*)d_in[0];
    const int*   mask  = (const int*)d_in[1];
    const float* ln1w  = (const float*)d_in[2];
    const float* ln1b  = (const float*)d_in[3];
    const float* qkvw  = (const float*)d_in[4];
    const float* projw = (const float*)d_in[5];
    const float* projb = (const float*)d_in[6];
    const float* ln2w  = (const float*)d_in[7];
    const float* ln2b  = (const float*)d_in[8];
    const float* fc1w  = (const float*)d_in[9];
    const float* fc1b  = (const float*)d_in[10];
    const float* fc2w  = (const float*)d_in[11];
    const float* fc2b  = (const float*)d_in[12];

    // Workspace (80 MB, lifetime reuse):
    //  [0,6M)    qkv_wT (dead after QKV gemm) | l_part [0,512K) during attn
    //  [6,8M)    proj_wT
    //  [8,16M)   fc1_wT
    //  [16,24M)  fc2_wT
    //  [24,32M)  ln_buf (ln1, later ln2)
    //  [32,40M)  q_buf   | h_buf [32,64M) at FC1
    //  [40,48M)  k_buf
    //  [48,56M)  attn_o (combine output)
    //  [56,64M)  vT_buf (written directly by QKV, transposed)
    //  [64,80M)  O_part (2 chunks x 32bh x 2048 x 64 bf16 = 16MB exactly)
    //            during attn; x1 fp32 after (PROJ overwrites fully)
    char* base = (char*)d_ws;
    unsigned short* qkv_wT  = (unsigned short*)(base);
    float*          l_part  = (float*)(base);                              // alias, post-QKV
    unsigned short* proj_wT = (unsigned short*)(base + (size_t)6  * 1024 * 1024);
    unsigned short* fc1_wT  = (unsigned short*)(base + (size_t)8  * 1024 * 1024);
    unsigned short* fc2_wT  = (unsigned short*)(base + (size_t)16 * 1024 * 1024);
    unsigned short* ln_buf  = (unsigned short*)(base + (size_t)24 * 1024 * 1024);
    unsigned short* q_buf   = (unsigned short*)(base + (size_t)32 * 1024 * 1024);
    unsigned short* k_buf   = (unsigned short*)(base + (size_t)40 * 1024 * 1024);
    unsigned short* attn_o  = (unsigned short*)(base + (size_t)48 * 1024 * 1024);
    unsigned short* vT_buf  = (unsigned short*)(base + (size_t)56 * 1024 * 1024);
    unsigned short* h_buf   = (unsigned short*)(base + (size_t)32 * 1024 * 1024); // reuse
    float*          x1      = (float*)(base + (size_t)64 * 1024 * 1024);
    unsigned short* opart   = (unsigned short*)(base + (size_t)64 * 1024 * 1024); // alias x1

    // 1. all 4 weight transposes + LN1 in ONE dispatch
    fused_pre<<<7168, 256, 0, stream>>>(qkvw, projw, fc1w, fc2w,
                                        qkv_wT, proj_wT, fc1_wT, fc2_wT,
                                        x, ln1w, ln1b, ln_buf);

    // 2. QKV GEMM -> q (pre-scaled by log2e/8), k [bh][t][d]; V DIRECTLY
    //    transposed into vT_buf [bh][d][t] (packed 8B stores).
    gemm_kernel<EP_QKV, 3072, 1024, 128, 128, 64><<<dim3(24, 32), 256, 0, stream>>>(
        ln_buf, qkv_wT, nullptr, nullptr, nullptr, q_buf, k_buf, vT_buf);

    // 3. attention partials: pair-balanced, 2-way split-K by kt parity
    //    (1024 blocks, 4 waves/SIMD, bh pinned to XCD)
    attn_partial2<<<1024, 256, 0, stream>>>(q_buf, k_buf, vT_buf, mask,
                                            opart, l_part);

    // 4. combine chunks -> attn_o
    attn_combine2<<<dim3(SEQ / 64, HEADS, BATCH), 256, 0, stream>>>(
        opart, l_part, attn_o);

    // 5. proj GEMM + residual(x fp32) -> x1 (O_part dead now; PROJ overwrites)
    gemm_kernel<EP_PROJ, 1024, 1024, 64, 64, 64><<<1024, 256, 0, stream>>>(
        attn_o, proj_wT, projb, x, x1, nullptr, nullptr, nullptr);

    // 6. LN2 (fp32 x1 -> bf16)
    ln_kernel<<<MTOK, 256, 0, stream>>>(x1, ln2w, ln2b, ln_buf);

    // 7. FC1 + GELU -> h_buf (bf16); TN=64, 2048 blocks, 48KB LDS (R9 win)
    gemm_kernel<EP_FC1, 4096, 1024, 128, 64, 64><<<dim3(64, 32), 256, 0, stream>>>(
        ln_buf, fc1_wT, fc1b, nullptr, h_buf, nullptr, nullptr, nullptr);

    // 8. FC2 + residual(x1) -> d_out
    gemm_kernel<EP_FC2, 1024, 4096, 64, 64, 64><<<1024, 256, 0, stream>>>(
        h_buf, fc2_wT, fc2b, x1, d_out, nullptr, nullptr, nullptr);
}

// Round 11
// 339.817 us; speedup vs baseline: 1.0721x; 1.0721x over previous
//
#include <hip/hip_runtime.h>
#include <stdint.h>

#define DIMC 1024
#define HEADS 16
#define HD 64
#define HIDDENC 4096
#define BATCH 2
#define SEQ 2048
#define MTOK (BATCH*SEQ)

typedef __bf16 bf16x8 __attribute__((ext_vector_type(8)));
typedef float f32x4 __attribute__((ext_vector_type(4)));

__device__ __forceinline__ float bf2f(unsigned short u) {
    union { unsigned int u; float f; } v; v.u = ((unsigned int)u) << 16; return v.f;
}
__device__ __forceinline__ unsigned short f2bf(float f) {
    union { float f; unsigned int u; } v; v.f = f;
    unsigned int r = v.u + 0x7fffu + ((v.u >> 16) & 1u);
    return (unsigned short)(r >> 16);
}
// pack 2 f32 -> 2 bf16 (RNE), src0 -> low half (T12 recipe, guide-verified)
__device__ __forceinline__ unsigned int cvt_pk_bf16(float lo, float hi) {
    unsigned int r;
    asm("v_cvt_pk_bf16_f32 %0, %1, %2" : "=v"(r) : "v"(lo), "v"(hi));
    return r;
}
// 2^x (log2e is pre-folded into the Q scale)
__device__ __forceinline__ float exp2_fast(float x) {
#if __has_builtin(__builtin_amdgcn_exp2f)
    return __builtin_amdgcn_exp2f(x);
#else
    float r;
    asm("v_exp_f32 %0, %1" : "=v"(r) : "v"(x));
    return r;
#endif
}

#define GLOAD_LDS(g, l) \
    __builtin_amdgcn_global_load_lds( \
        (const __attribute__((address_space(1))) void*)(g), \
        (__attribute__((address_space(3))) void*)(l), 16, 0, 0)

// ---------------------------------------------------------------------------
// Weight transpose tile: fp32 (K x N) -> bf16 (N x K).
// ---------------------------------------------------------------------------
__device__ __forceinline__ void tp_tile(const float* __restrict__ in,
                                        unsigned short* __restrict__ out,
                                        int K, int N, int tn, int tk, int tid,
                                        unsigned short (*tile)[65]) {
    for (int c = tid; c < 1024; c += 256) {
        int r = c >> 4, coff = (c & 15) * 4;
        float4 v = *(const float4*)(in + (size_t)(tk + r) * N + tn + coff);
        tile[r][coff + 0] = f2bf(v.x);
        tile[r][coff + 1] = f2bf(v.y);
        tile[r][coff + 2] = f2bf(v.z);
        tile[r][coff + 3] = f2bf(v.w);
    }
    __syncthreads();
    for (int c = tid; c < 512; c += 256) {
        int rn = c >> 3, off = (c & 7) * 8;
        unsigned short tmp[8];
        #pragma unroll
        for (int j = 0; j < 8; j++) tmp[j] = tile[off + j][rn];
        *(uint4*)(out + (size_t)(tn + rn) * K + tk + off) = *(uint4*)tmp;
    }
}

// ---------------------------------------------------------------------------
// LayerNorm row body (shared by fused_pre and ln_kernel).
// ---------------------------------------------------------------------------
__device__ __forceinline__ void ln_row(const float* __restrict__ inp,
                                       const float* __restrict__ w,
                                       const float* __restrict__ b,
                                       unsigned short* __restrict__ out,
                                       int row, int tid, float* red) {
    int base = tid * 4;
    float4 v = *(const float4*)(inp + (size_t)row * DIMC + base);
    float x[4] = {v.x, v.y, v.z, v.w};
    float s1 = x[0] + x[1] + x[2] + x[3];
    float s2 = x[0]*x[0] + x[1]*x[1] + x[2]*x[2] + x[3]*x[3];
    #pragma unroll
    for (int off = 32; off > 0; off >>= 1) {
        s1 += __shfl_xor(s1, off);
        s2 += __shfl_xor(s2, off);
    }
    int wv = tid >> 6;
    if ((tid & 63) == 0) { red[wv] = s1; red[4 + wv] = s2; }
    __syncthreads();
    s1 = red[0] + red[1] + red[2] + red[3];
    s2 = red[4] + red[5] + red[6] + red[7];
    float mean = s1 * (1.0f / DIMC);
    float var  = s2 * (1.0f / DIMC) - mean * mean;
    float rstd = rsqrtf(var + 1e-5f);
    float4 wv4 = *(const float4*)(w + base);
    float4 bv4 = *(const float4*)(b + base);
    ushort4 o;
    o.x = f2bf((x[0] - mean) * rstd * wv4.x + bv4.x);
    o.y = f2bf((x[1] - mean) * rstd * wv4.y + bv4.y);
    o.z = f2bf((x[2] - mean) * rstd * wv4.z + bv4.z);
    o.w = f2bf((x[3] - mean) * rstd * wv4.w + bv4.w);
    *(ushort4*)(out + (size_t)row * DIMC + base) = o;
}

// ---------------------------------------------------------------------------
// fused_pre: all 4 weight transposes + LN1 in ONE dispatch (independent work).
// Blocks [0,3072): transposes; [3072,7168): LN1 rows.
// ---------------------------------------------------------------------------
__global__ __launch_bounds__(256) void fused_pre(
    const float* __restrict__ qkvw, const float* __restrict__ projw,
    const float* __restrict__ fc1w, const float* __restrict__ fc2w,
    unsigned short* __restrict__ qkv_wT, unsigned short* __restrict__ proj_wT,
    unsigned short* __restrict__ fc1_wT, unsigned short* __restrict__ fc2_wT,
    const float* __restrict__ x, const float* __restrict__ ln1w,
    const float* __restrict__ ln1b, unsigned short* __restrict__ ln_out) {
    __shared__ unsigned short tile[64][65];
    __shared__ float red[8];
    int id = blockIdx.x, tid = threadIdx.x;
    if (id < 768) {
        tp_tile(qkvw, qkv_wT, 1024, 3072, (id % 48) * 64, (id / 48) * 64, tid, tile);
    } else if (id < 1024) {
        id -= 768;
        tp_tile(projw, proj_wT, 1024, 1024, (id % 16) * 64, (id / 16) * 64, tid, tile);
    } else if (id < 2048) {
        id -= 1024;
        tp_tile(fc1w, fc1_wT, 1024, 4096, (id % 64) * 64, (id / 64) * 64, tid, tile);
    } else if (id < 3072) {
        id -= 2048;
        tp_tile(fc2w, fc2_wT, 4096, 1024, (id % 16) * 64, (id / 16) * 64, tid, tile);
    } else {
        ln_row(x, ln1w, ln1b, ln_out, id - 3072, tid, red);
    }
}

// ---------------------------------------------------------------------------
// LayerNorm kernel (LN2).
// ---------------------------------------------------------------------------
__global__ __launch_bounds__(256) void ln_kernel(const float* __restrict__ inp,
                                                 const float* __restrict__ w,
                                                 const float* __restrict__ b,
                                                 unsigned short* __restrict__ out) {
    __shared__ float red[8];
    ln_row(inp, w, b, out, blockIdx.x, threadIdx.x, red);
}

// ---------------------------------------------------------------------------
// bf16 MFMA GEMM: C(M x N) = A(M x K) @ BT(N x K)^T.
// Tile TM x TN, 4 waves (2x2), XOR-swizzled LDS, global_load_lds staging,
// double-buffered with counted vmcnt (R4).
//
// Mapping (A/B-measured):
//  - QKV (128x128), FC1 (128x64, R9): 2D dim3 grid. R5 rectangle REGRESSED
//    FC1 (lockstep A-panel reads); dim3 spreads co-resident blocks.
//  - PROJ/FC2 (64x64): 1D XCD rectangle (MG=4 x NG=2). R4: naive dim3 gave
//    A-dup=8, FETCH 143MB.
// ---------------------------------------------------------------------------
enum { EP_QKV = 0, EP_PROJ = 1, EP_FC1 = 2, EP_FC2 = 3 };

template <int MODE, int N, int K, int TM, int TN, int BK>
__global__ __launch_bounds__(256) void gemm_kernel(
    const unsigned short* __restrict__ A,
    const unsigned short* __restrict__ BT,
    const float* __restrict__ bias,
    const float* __restrict__ res,      // fp32 residual (PROJ: x, FC2: x1)
    void* __restrict__ out0,
    unsigned short* __restrict__ q_buf,
    unsigned short* __restrict__ k_buf,
    unsigned short* __restrict__ v_buf) {  // QKV: vT_buf [bh][d][t]
    constexpr int MI = TM / 32;
    constexpr int NJ = TN / 32;
    constexpr int CPR = BK / 8;
    constexpr int NT = K / BK;
    constexpr int N_LD = (TM + TN) * BK / 2048;
    static_assert(N_LD == 8 || N_LD == 6 || N_LD == 4, "vmcnt literal");
    constexpr int NX = N / TN;
    constexpr int NY = MTOK / TM;
    constexpr int MG = 4, NG = 2;
    constexpr int NXG = NX / NG, NYG = NY / MG;

    __shared__ __align__(16) unsigned short As[2 * TM * BK];
    __shared__ __align__(16) unsigned short Bs[2 * TN * BK];
    const int tid = threadIdx.x;

    int m0, n0;
    if constexpr (MODE == EP_PROJ || MODE == EP_FC2) {
        const int jb = blockIdx.x;
        const int xcd = jb & 7;
        const int tb = jb >> 3;
        const int mg = xcd >> 1, ng = xcd & 1;
        m0 = (mg * NYG + tb / NXG) * TM;
        n0 = (ng * NXG + tb % NXG) * TN;
    } else {
        m0 = blockIdx.y * TM;
        n0 = blockIdx.x * TN;
    }

    const int wave = tid >> 6, lane = tid & 63;
    const int wm = wave >> 1, wn = wave & 1;
    const int quad = lane >> 4, l16 = lane & 15;
    const int swz = l16 & (CPR - 1);

    f32x4 acc[MI][NJ] = {};

    auto stage = [&](int t, int b) {
        const size_t kk = (size_t)t * BK;
        #pragma unroll
        for (int it = 0; it < TM * BK / 2048; ++it) {
            int c = tid + 256 * it;
            int row = c / CPR, jj = c % CPR;
            int col8 = (jj ^ (row & (CPR - 1))) * 8;
            GLOAD_LDS(A + (size_t)(m0 + row) * K + kk + col8,
                      As + (size_t)b * TM * BK + (size_t)c * 8);
        }
        #pragma unroll
        for (int it = 0; it < TN * BK / 2048; ++it) {
            int c = tid + 256 * it;
            int row = c / CPR, jj = c % CPR;
            int col8 = (jj ^ (row & (CPR - 1))) * 8;
            GLOAD_LDS(BT + (size_t)(n0 + row) * K + kk + col8,
                      Bs + (size_t)b * TN * BK + (size_t)c * 8);
        }
    };

    stage(0, 0);
    for (int t = 0; t < NT; ++t) {
        const int cur = t & 1;
        if (t + 1 < NT) {
            stage(t + 1, cur ^ 1);
            if constexpr (N_LD == 8)      asm volatile("s_waitcnt vmcnt(8)" ::: "memory");
            else if constexpr (N_LD == 6) asm volatile("s_waitcnt vmcnt(6)" ::: "memory");
            else                          asm volatile("s_waitcnt vmcnt(4)" ::: "memory");
        } else {
            asm volatile("s_waitcnt vmcnt(0)" ::: "memory");
        }
        __builtin_amdgcn_s_barrier();

        const unsigned short* Asb = As + (size_t)cur * TM * BK;
        const unsigned short* Bsb = Bs + (size_t)cur * TN * BK;
        #pragma unroll
        for (int kk2 = 0; kk2 < BK / 32; ++kk2) {
            bf16x8 af[MI], bfv[NJ];
            #pragma unroll
            for (int i = 0; i < MI; i++) {
                int row = 16 * MI * wm + 16 * i + l16;
                int sj = (4 * kk2 + quad) ^ swz;
                af[i] = *(const bf16x8*)&Asb[row * BK + sj * 8];
            }
            #pragma unroll
            for (int j = 0; j < NJ; j++) {
                int row = 16 * NJ * wn + 16 * j + l16;
                int sj = (4 * kk2 + quad) ^ swz;
                bfv[j] = *(const bf16x8*)&Bsb[row * BK + sj * 8];
            }
            #pragma unroll
            for (int i = 0; i < MI; i++)
                #pragma unroll
                for (int j = 0; j < NJ; j++)
                    acc[i][j] = __builtin_amdgcn_mfma_f32_16x16x32_bf16(af[i], bfv[j], acc[i][j], 0, 0, 0);
        }
        asm volatile("s_waitcnt lgkmcnt(0)" ::: "memory");
        __builtin_amdgcn_s_barrier();
    }

    #pragma unroll
    for (int i = 0; i < MI; i++) {
        #pragma unroll
        for (int j = 0; j < NJ; j++) {
            int nl = n0 + 16 * NJ * wn + 16 * j + l16;
            if (MODE == EP_QKV) {
                int which = nl >> 10, rem = nl & 1023;
                int hh = rem >> 6, d = rem & 63;
                int ml0 = m0 + 16 * MI * wm + 16 * i + quad * 4;
                int bb2 = ml0 >> 11, t0 = ml0 & 2047;
                int bh = bb2 * HEADS + hh;
                if (which == 2) {
                    uint2 w;
                    w.x = cvt_pk_bf16(acc[i][j][0], acc[i][j][1]);
                    w.y = cvt_pk_bf16(acc[i][j][2], acc[i][j][3]);
                    *(uint2*)(v_buf + ((size_t)bh * HD + d) * SEQ + t0) = w;
                } else if (which == 0) {
                    #pragma unroll
                    for (int r = 0; r < 4; r++)
                        q_buf[((size_t)bh * SEQ + t0 + r) * HD + d] =
                            f2bf(acc[i][j][r] * 0.18033688011112042f);
                } else {
                    #pragma unroll
                    for (int r = 0; r < 4; r++)
                        k_buf[((size_t)bh * SEQ + t0 + r) * HD + d] = f2bf(acc[i][j][r]);
                }
            } else {
                float bval = bias[nl];
                #pragma unroll
                for (int r = 0; r < 4; r++) {
                    int ml = m0 + 16 * MI * wm + 16 * i + quad * 4 + r;
                    float v = acc[i][j][r];
                    if (MODE == EP_PROJ) {
                        float* x1 = (float*)out0;
                        x1[(size_t)ml * DIMC + nl] = res[(size_t)ml * DIMC + nl] + v + bval;
                    } else if (MODE == EP_FC1) {
                        float g = v + bval;
                        float u = 1.5957691216f * (g + 0.044715f * g * g * g);
                        float gv = g / (1.0f + __expf(-u));
                        ((unsigned short*)out0)[(size_t)ml * HIDDENC + nl] = f2bf(gv);
                    } else {
                        ((float*)out0)[(size_t)ml * DIMC + nl] =
                            res[(size_t)ml * DIMC + nl] + v + bval;
                    }
                }
            }
        }
    }
}

// ---------------------------------------------------------------------------
// Flash attention, pair-balanced + 2-WAY SPLIT-K (R10) — R11 fixes:
//  - launch_bounds(256,3): R10's (256,4) capped VGPR at 128 and the compiler
//    landed at 64 (< the ~85 the kernel needs) -> scratch spill traffic
//    (WRITE 155MB, FETCH +16MB, dur 85us). Cap 170 removes the starvation.
//  - pair-interleave DROPPED (R9 measured it neutral): sequential R8-style
//    per-tile passes, single Ps buffer -> lower peak pressure, LDS 27136.
// Grid 1024: block (pair p, bh, chunk c): kt = c, c+2, ...; 16/17 units,
// uniform. Writes UNNORMALIZED bf16 O + lsum; combine divides by l0+l1.
//
// Key-padding: masked keys get CONSTANT 1e-13 (uniform when row fully masked,
// matching ref fp32 +(-1e9)). Swapped QK^T; P via cvt_pk+ds_write_b64 into
// wave-private XOR-swizzled Ps; PV A-read = contiguous ds_read_b128.
// ---------------------------------------------------------------------------
#define KP 72
#define PMASK 1e-13f
__global__ __launch_bounds__(256, 3) void attn_partial2(
    const unsigned short* __restrict__ q_buf,
    const unsigned short* __restrict__ k_buf,
    const unsigned short* __restrict__ vT_buf,
    const int* __restrict__ mask,
    unsigned short* __restrict__ opart,   // [c][bh][t][d], bf16, 16MB
    float* __restrict__ l_part) {         // [c][bh][t], f32
    __shared__ __align__(16) unsigned short Ks[64 * KP];
    __shared__ __align__(16) unsigned short Vs[64 * KP];
    __shared__ __align__(16) unsigned short Ps[4 * 16 * 64];  // per-wave swizzled P / O-stage
    __shared__ __align__(16) float Msf[64];

    // decode: xcd = j&7 pins bh group to XCD; c = chunk parity; p = pair.
    const int j = blockIdx.x;            // 0..1023
    const int xcd = j & 7;
    const int t = j >> 3;                // 0..127
    const int c = t & 1;
    const int t2 = t >> 1;               // 0..63
    const int bhg = t2 & 3;
    const int p = t2 >> 2;               // 0..15
    const int bh = bhg * 8 + xcd;        // 0..31
    const int bb = bh >> 4, h = bh & 15;
    const int qa = 31 - p, qb = p;       // qa > qb always
    const int kta = qa + 1;

    const int tid = threadIdx.x, wave = tid >> 6, lane = tid & 63;
    const int quad = lane >> 4, l16 = lane & 15;
    const unsigned short* qp = q_buf + (size_t)bh * SEQ * HD;
    const unsigned short* kp = k_buf + (size_t)bh * SEQ * HD;
    const unsigned short* vp = vT_buf + (size_t)bh * HD * SEQ;
    const int* mrow_ptr = mask + bb * SEQ;

    const int qrow_a = qa * 64 + wave * 16 + l16;
    const int qrow_b = qb * 64 + wave * 16 + l16;
    bf16x8 qfa[2], qfb[2];
    qfa[0] = *(const bf16x8*)(qp + (size_t)qrow_a * HD + 8 * quad);
    qfa[1] = *(const bf16x8*)(qp + (size_t)qrow_a * HD + 32 + 8 * quad);
    qfb[0] = *(const bf16x8*)(qp + (size_t)qrow_b * HD + 8 * quad);
    qfb[1] = *(const bf16x8*)(qp + (size_t)qrow_b * HD + 32 + 8 * quad);

    f32x4 oa[4] = {}, ob4[4] = {};
    float lsa = 0.0f, lsb = 0.0f;

    const int r0 = tid >> 3, c0 = (tid & 7) * 8;
    const int r1 = r0 + 32;

    char* psb = (char*)Ps + wave * 2048 + l16 * 128;
    const int swz = (l16 & 7) << 4;

    // one q-tile pass over the staged tile kt (wave-uniform control)
    auto do_qtile = [&](const bf16x8* qf, f32x4* o, float& ls,
                        int qt_, int qrow_, int kt) {
        f32x4 sc[4];
        __builtin_amdgcn_s_setprio(1);
        #pragma unroll
        for (int ct = 0; ct < 4; ct++) {
            f32x4 z = {};
            #pragma unroll
            for (int ss = 0; ss < 2; ss++) {
                bf16x8 kf = *(const bf16x8*)&Ks[(16 * ct + l16) * KP + 32 * ss + 8 * quad];
                z = __builtin_amdgcn_mfma_f32_16x16x32_bf16(kf, qf[ss], z, 0, 0, 0);
            }
            sc[ct] = z;
        }
        __builtin_amdgcn_s_setprio(0);

        const bool diag = (kt == qt_);
        #pragma unroll
        for (int ct = 0; ct < 4; ct++) {
            float4 mq = *(const float4*)&Msf[16 * ct + 4 * quad];
            float mfs[4] = {mq.x, mq.y, mq.z, mq.w};
            const int kg0 = kt * 64 + 16 * ct + 4 * quad;
            float pv4[4];
            #pragma unroll
            for (int r = 0; r < 4; r++) {
                float pw = (mfs[r] != 0.0f) ? PMASK : exp2_fast(sc[ct][r]);
                if (diag && (kg0 + r) > qrow_) pw = 0.0f;
                ls += pw;
                pv4[r] = pw;
            }
            uint2 w;
            w.x = cvt_pk_bf16(pv4[0], pv4[1]);
            w.y = cvt_pk_bf16(pv4[2], pv4[3]);
            *(uint2*)(psb + ((quad * 8 + ct * 32) ^ swz)) = w;
        }
        asm volatile("" ::: "memory");   // order punned LDS write -> read

        __builtin_amdgcn_s_setprio(1);
        #pragma unroll
        for (int ss = 0; ss < 2; ss++) {
            bf16x8 pf = *(const bf16x8*)(psb + ((ss * 64 + quad * 16) ^ swz));
            #pragma unroll
            for (int dt = 0; dt < 4; dt++) {
                bf16x8 vf = *(const bf16x8*)&Vs[(16 * dt + l16) * KP + 32 * ss + 8 * quad];
                o[dt] = __builtin_amdgcn_mfma_f32_16x16x32_bf16(pf, vf, o[dt], 0, 0, 0);
            }
        }
        __builtin_amdgcn_s_setprio(0);
        asm volatile("" ::: "memory");   // order PV reads before next Ps overwrite
    };

    // prefetch first tile (kt = c); Msf holds 1.0 = masked, 0.0 = visible
    uint4 pk0, pk1, pv0, pv1; float pmv = 0.0f;
    pk0 = *(const uint4*)(kp + (size_t)(c * 64 + r0) * HD + c0);
    pk1 = *(const uint4*)(kp + (size_t)(c * 64 + r1) * HD + c0);
    pv0 = *(const uint4*)(vp + (size_t)r0 * SEQ + c * 64 + c0);
    pv1 = *(const uint4*)(vp + (size_t)r1 * SEQ + c * 64 + c0);
    if (tid < 64) pmv = mrow_ptr[c * 64 + tid] ? 1.0f : 0.0f;

    for (int kt = c; kt < kta; kt += 2) {
        __syncthreads();
        *(uint4*)&Ks[r0 * KP + c0] = pk0;
        *(uint4*)&Ks[r1 * KP + c0] = pk1;
        *(uint4*)&Vs[r0 * KP + c0] = pv0;
        *(uint4*)&Vs[r1 * KP + c0] = pv1;
        if (tid < 64) Msf[tid] = pmv;
        if (kt + 2 < kta) {
            pk0 = *(const uint4*)(kp + (size_t)((kt + 2) * 64 + r0) * HD + c0);
            pk1 = *(const uint4*)(kp + (size_t)((kt + 2) * 64 + r1) * HD + c0);
            pv0 = *(const uint4*)(vp + (size_t)r0 * SEQ + (kt + 2) * 64 + c0);
            pv1 = *(const uint4*)(vp + (size_t)r1 * SEQ + (kt + 2) * 64 + c0);
            if (tid < 64) pmv = mrow_ptr[(kt + 2) * 64 + tid] ? 1.0f : 0.0f;
        }
        __syncthreads();

        do_qtile(qfa, oa, lsa, qa, qrow_a, kt);          // always
        if (kt <= qb)
            do_qtile(qfb, ob4, lsb, qb, qrow_b, kt);     // shared K/V tile
    }

    // store UNNORMALIZED O (staged via wave-private Ps for full-line writes)
    // + per-chunk lsum. Combine kernel normalizes by l0+l1.
    unsigned short* Ls = Ps + wave * 1024;
    auto finishp = [&](const f32x4* o, float ls, int qt_) {
        ls += __shfl_xor(ls, 16);
        ls += __shfl_xor(ls, 32);
        if (lane < 16)
            l_part[(size_t)(c * 32 + bh) * SEQ + qt_ * 64 + wave * 16 + lane] = ls;
        #pragma unroll
        for (int dt = 0; dt < 4; dt++)
            #pragma unroll
            for (int r = 0; r < 4; r++)
                Ls[(quad * 4 + r) * 64 + 16 * dt + l16] = f2bf(o[dt][r]);
        asm volatile("" ::: "memory");
        unsigned short* obp = opart +
            ((size_t)(c * 32 + bh) * SEQ + qt_ * 64 + wave * 16) * 64;
        *(uint4*)(obp + lane * 8) = *(const uint4*)&Ls[lane * 8];
        *(uint4*)(obp + 512 + lane * 8) = *(const uint4*)&Ls[512 + lane * 8];
        asm volatile("" ::: "memory");
    };
    finishp(oa, lsa, qa);
    finishp(ob4, lsb, qb);
}

// ---------------------------------------------------------------------------
// Combine the 2 split-K chunks: attn_o = (O0 + O1) / (l0 + l1), bf16.
// One block per (qt, h, b); vectorized uint4 (R6-proven pattern, n=2).
// ---------------------------------------------------------------------------
__global__ __launch_bounds__(256) void attn_combine2(
    const unsigned short* __restrict__ opart,
    const float* __restrict__ l_part,
    unsigned short* __restrict__ attn_o) {
    const int qt = blockIdx.x, h = blockIdx.y, bb = blockIdx.z;
    const int bh = bb * HEADS + h;
    const int tid = threadIdx.x;
    __shared__ float linv[64];
    if (tid < 64) {
        float l0 = l_part[(size_t)bh * SEQ + qt * 64 + tid];
        float l1 = l_part[(size_t)(32 + bh) * SEQ + qt * 64 + tid];
        linv[tid] = 1.0f / (l0 + l1);
    }
    __syncthreads();
    const unsigned short* o0 = opart + ((size_t)bh * SEQ + qt * 64) * 64;
    const unsigned short* o1 = opart + ((size_t)(32 + bh) * SEQ + qt * 64) * 64;
    #pragma unroll
    for (int it = 0; it < 2; it++) {
        int idx = (it * 256 + tid) * 8;      // 0..4088
        int row = idx >> 6, d = idx & 63;
        uint4 va = *(const uint4*)(o0 + idx);
        uint4 vb = *(const uint4*)(o1 + idx);
        const unsigned short* pa = (const unsigned short*)&va;
        const unsigned short* pb = (const unsigned short*)&vb;
        float sc = linv[row];
        unsigned short tmp[8];
        #pragma unroll
        for (int e = 0; e < 8; e++)
            tmp[e] = f2bf((bf2f(pa[e]) + bf2f(pb[e])) * sc);
        *(uint4*)(attn_o + ((size_t)(bb * SEQ + qt * 64 + row)) * DIMC + h * HD + d) =
            *(uint4*)tmp;
    }
}

// ---------------------------------------------------------------------------
extern "C" void kernel_launch(void* const* d_in, const int* in_sizes, int n_in,
                              void* d_out, int out_size, void* d_ws, size_t ws_size,
                              hipStream_t stream) {
    const float* x     = (const float*)d_in[0];
    const int*   mask  = (const int*)d_in[1];
    const float* ln1w  = (const float*)d_in[2];
    const float* ln1b  = (const float*)d_in[3];
    const float* qkvw  = (const float*)d_in[4];
    const float* projw = (const float*)d_in[5];
    const float* projb = (const float*)d_in[6];
    const float* ln2w  = (const float*)d_in[7];
    const float* ln2b  = (const float*)d_in[8];
    const float* fc1w  = (const float*)d_in[9];
    const float* fc1b  = (const float*)d_in[10];
    const float* fc2w  = (const float*)d_in[11];
    const float* fc2b  = (const float*)d_in[12];

    // Workspace (80 MB, lifetime reuse):
    //  [0,6M)    qkv_wT (dead after QKV gemm) | l_part [0,512K) during attn
    //  [6,8M)    proj_wT
    //  [8,16M)   fc1_wT
    //  [16,24M)  fc2_wT
    //  [24,32M)  ln_buf (ln1, later ln2)
    //  [32,40M)  q_buf   | h_buf [32,64M) at FC1
    //  [40,48M)  k_buf
    //  [48,56M)  attn_o (combine output)
    //  [56,64M)  vT_buf (written directly by QKV, transposed)
    //  [64,80M)  O_part (2 chunks x 32bh x 2048 x 64 bf16 = 16MB exactly)
    //            during attn; x1 fp32 after (PROJ overwrites fully)
    char* base = (char*)d_ws;
    unsigned short* qkv_wT  = (unsigned short*)(base);
    float*          l_part  = (float*)(base);                              // alias, post-QKV
    unsigned short* proj_wT = (unsigned short*)(base + (size_t)6  * 1024 * 1024);
    unsigned short* fc1_wT  = (unsigned short*)(base + (size_t)8  * 1024 * 1024);
    unsigned short* fc2_wT  = (unsigned short*)(base + (size_t)16 * 1024 * 1024);
    unsigned short* ln_buf  = (unsigned short*)(base + (size_t)24 * 1024 * 1024);
    unsigned short* q_buf   = (unsigned short*)(base + (size_t)32 * 1024 * 1024);
    unsigned short* k_buf   = (unsigned short*)(base + (size_t)40 * 1024 * 1024);
    unsigned short* attn_o  = (unsigned short*)(base + (size_t)48 * 1024 * 1024);
    unsigned short* vT_buf  = (unsigned short*)(base + (size_t)56 * 1024 * 1024);
    unsigned short* h_buf   = (unsigned short*)(base + (size_t)32 * 1024 * 1024); // reuse
    float*          x1      = (float*)(base + (size_t)64 * 1024 * 1024);
    unsigned short* opart   = (unsigned short*)(base + (size_t)64 * 1024 * 1024); // alias x1

    // 1. all 4 weight transposes + LN1 in ONE dispatch
    fused_pre<<<7168, 256, 0, stream>>>(qkvw, projw, fc1w, fc2w,
                                        qkv_wT, proj_wT, fc1_wT, fc2_wT,
                                        x, ln1w, ln1b, ln_buf);

    // 2. QKV GEMM -> q (pre-scaled by log2e/8), k [bh][t][d]; V DIRECTLY
    //    transposed into vT_buf [bh][d][t] (packed 8B stores).
    gemm_kernel<EP_QKV, 3072, 1024, 128, 128, 64><<<dim3(24, 32), 256, 0, stream>>>(
        ln_buf, qkv_wT, nullptr, nullptr, nullptr, q_buf, k_buf, vT_buf);

    // 3. attention partials: pair-balanced, 2-way split-K by kt parity
    //    (1024 blocks, bh pinned to XCD)
    attn_partial2<<<1024, 256, 0, stream>>>(q_buf, k_buf, vT_buf, mask,
                                            opart, l_part);

    // 4. combine chunks -> attn_o
    attn_combine2<<<dim3(SEQ / 64, HEADS, BATCH), 256, 0, stream>>>(
        opart, l_part, attn_o);

    // 5. proj GEMM + residual(x fp32) -> x1 (O_part dead now; PROJ overwrites)
    gemm_kernel<EP_PROJ, 1024, 1024, 64, 64, 64><<<1024, 256, 0, stream>>>(
        attn_o, proj_wT, projb, x, x1, nullptr, nullptr, nullptr);

    // 6. LN2 (fp32 x1 -> bf16)
    ln_kernel<<<MTOK, 256, 0, stream>>>(x1, ln2w, ln2b, ln_buf);

    // 7. FC1 + GELU -> h_buf (bf16); TN=64, 2048 blocks, 48KB LDS (R9 win)
    gemm_kernel<EP_FC1, 4096, 1024, 128, 64, 64><<<dim3(64, 32), 256, 0, stream>>>(
        ln_buf, fc1_wT, fc1b, nullptr, h_buf, nullptr, nullptr, nullptr);

    // 8. FC2 + residual(x1) -> d_out
    gemm_kernel<EP_FC2, 1024, 4096, 64, 64, 64><<<1024, 256, 0, stream>>>(
        h_buf, fc2_wT, fc2b, x1, d_out, nullptr, nullptr, nullptr);
}